// Round 2
// baseline (3303.930 us; speedup 1.0000x reference)
//
#include <hip/hip_runtime.h>
#include <cstdint>

// Problem constants (from reference)
#define VN 100000   // vocab
#define DD 128      // D
#define BB 512      // batch
#define LL 20       // session length
#define TT 20       // time steps
#define HH 32       // H
#define CC 33       // C = H+1
#define NC (HH*CC)  // 1056

typedef unsigned int u32;

#define DEV static __device__ __forceinline__

DEV float tanh_fast(float x){ float e=__expf(2.f*x); return 1.f - 2.f/(e+1.f); }

// broadcast a lane's value wave-wide via v_readlane -> SGPR (folds into v_fma scalar src)
DEV float rdlane(float v, int l){
  return __int_as_float(__builtin_amdgcn_readlane(__float_as_int(v), l));
}

// ================= K1: fused knots + CDE RK4 scan ==========================
// g=2 rows/block, 256 blocks (1 block/CU), 512 threads = 8 waves = 2/SIMD.
// __launch_bounds__(512,2) -> 256-VGPR cap, so the 128-float cached w2 row
// (~210 VGPR total demand) is actually allocatable (round-1 spilled at 84).
// Thread (h=t>>4,q=t&15): row h*33+q cached in VGPRs, row h*33+16+q streamed
// from L2 per stage (64B/lane chunks, double-buffered, issued before the h1
// barrier to hide L2 latency). Tail rows h*33+32: lane-parallel per wave +
// full-wave butterfly. h1 broadcast via v_readlane (compile-time lane idx).
__global__ __launch_bounds__(512, 2) void k_cde(
    const float* __restrict__ emb, const int* __restrict__ eids,
    const float* __restrict__ times,
    const float* __restrict__ red_w, const float* __restrict__ red_b,
    const float* __restrict__ w1, const float* __restrict__ b1,
    const float* __restrict__ w2, const float* __restrict__ b2,
    const float* __restrict__ iw, const float* __restrict__ ib,
    const float* __restrict__ rw, const float* __restrict__ rb,
    float* __restrict__ te){
  __shared__ float s_u[40*DD + 32*129];  // phase1: er(5120)|rw(4128); phase2: w1 (128*33)
  __shared__ float s_X[2*TT*CC];         // [g][t][c], persistent
  __shared__ float s_b1[DD];
  __shared__ float s_h1[2*DD];           // [g][j]
  __shared__ float s_z[64], s_zs[64], s_ks[64], s_kp[64], s_kt[64];
  __shared__ float s_dx[2*CC];
  const int t = threadIdx.x;
  const int b0 = blockIdx.x*2;
  const int lane = t & 63;
  const int wv = t >> 6;                 // wave 0..7
  const int h  = t >> 4;                 // 0..31
  const int q  = t & 15;                 // 0..15
  float* s_er = s_u;
  float* s_rw = s_u + 40*DD;             // phase1, rows padded to 129
  float* s_w1 = s_u;                     // phase2 alias, [j*33+h]

  // ---- register-cache w2 row Rc = h*33+q (one-time, overlaps phase 1) ----
  float w2c[DD];
  {
    const float4* rc4 = (const float4*)(w2 + (size_t)(h*CC+q)*DD);
    #pragma unroll
    for (int j4=0;j4<32;j4++){
      float4 v = rc4[j4];
      w2c[4*j4]=v.x; w2c[4*j4+1]=v.y; w2c[4*j4+2]=v.z; w2c[4*j4+3]=v.w;
    }
  }
  const float b2c = b2[h*CC+q];
  const float b2s = b2[h*CC+16+q];
  const float* rs = w2 + (size_t)(h*CC+16+q)*DD;   // streamed row
  // tail rows n=(4wv+r)*33+32: lane holds w2[n][lane], w2[n][64+lane]
  float w2t[8], b2t[4];
  #pragma unroll
  for (int r=0;r<4;r++){
    const float* tr = w2 + (size_t)((4*wv+r)*CC+32)*DD;
    w2t[2*r]   = tr[lane];
    w2t[2*r+1] = tr[64+lane];
    b2t[r]     = b2[(4*wv+r)*CC+32];
  }

  // ---- phase 1: knots X[g][t][:] ----
  for (int i=t;i<HH*DD;i+=512){ int hh=i>>7, d=i&127; s_rw[hh*129+d]=red_w[i]; }
  if (t<40){ int g=t/TT, tt2=t%TT; s_X[(g*TT+tt2)*CC]=times[(b0+g)*TT+tt2]; }
  for (int pi=t;pi<40*DD;pi+=512){ int r=pi>>7, e=pi&127;
      s_er[pi]=emb[(size_t)eids[b0*TT+r]*DD+e]; }
  __syncthreads();
  for (int task=t; task<40*HH; task+=512){   // 512%32==0 -> shuffle groups aligned
    int r=task>>5, hh=task&31;
    const float* wr=s_rw+hh*129;
    const float* er=s_er+(size_t)r*DD;
    float acc=red_b[hh];
    #pragma unroll 16
    for(int e=0;e<DD;e++) acc += er[e]*wr[e];
    float ssq=acc*acc;
    #pragma unroll
    for(int o=16;o>0;o>>=1) ssq+=__shfl_xor(ssq,o,32);
    s_X[r*CC+1+hh]=acc/(sqrtf(ssq)+1e-12f);   // fode = l2n(...) into X[...,1+h]
  }
  __syncthreads();                            // fode readers done; union free
  // ---- phase 2 weights: w1 (stride 33, conflict-free b32 reads), b1 ----
  for (int i=t;i<DD*HH;i+=512){ int j=i>>5, hh=i&31; s_w1[j*33+hh]=w1[i]; }
  if (t<DD) s_b1[t]=b1[t];
  // ---- z0 = X[:,0] @ init_w.T + init_b ----
  if (t<64){
    int g=t>>5, hh=t&31;
    float acc=ib[hh];
    const float* x0=s_X+(size_t)(g*TT)*CC;
    #pragma unroll
    for(int c=0;c<CC;c++) acc += x0[c]*iw[hh*CC+c];
    s_z[t]=acc; s_zs[t]=acc;
  }
  __syncthreads();   // w1/b1/z0 ready

  const float4* rs4=(const float4*)rs;
  for (int step=0; step<TT-1; step++){
    if (t<2*CC){ int g=t/CC, c=t-g*CC;
      s_dx[t]=s_X[(g*TT+step+1)*CC+c]-s_X[(g*TT+step)*CC+c]; }
    // (prev readers of s_dx finished before last sync; new readers wait for sync_A)
    for (int s=0;s<4;s++){
      // prefetch streamed chunk 0 early (no h1 dependency -> hides L2 latency)
      float4 c0=rs4[0], c1=rs4[1], c2=rs4[2], c3=rs4[3];
      // ---- stage A: h1 = relu(zs @ w1.T + b1) ----
      if (t<256){
        const int g=t>>7, j=t&127, gb=(t>>7)*32;
        float zsv=s_zs[lane];
        float acc=s_b1[j];
        const float* wj=s_w1+j*33;
        #pragma unroll
        for(int hh=0;hh<HH;hh++) acc += rdlane(zsv, gb+hh)*wj[hh];
        s_h1[g*DD+j]=fmaxf(acc,0.f);
      }
      __syncthreads();   // sync_A: h1 (and s_dx) ready
      {
        float h00=s_h1[lane],    h01=s_h1[64+lane];     // g=0
        float h10=s_h1[DD+lane], h11=s_h1[DD+64+lane];  // g=1
        float a00=b2c, a01=b2c, a10=b2s, a11=b2s;       // acc[row][g]
        #pragma unroll
        for (int jc=0;jc<8;jc++){
          float4 n0=c0,n1=c1,n2=c2,n3=c3;
          if (jc<7){ n0=rs4[4*jc+4]; n1=rs4[4*jc+5]; n2=rs4[4*jc+6]; n3=rs4[4*jc+7]; }
          float cf[16]={c0.x,c0.y,c0.z,c0.w, c1.x,c1.y,c1.z,c1.w,
                        c2.x,c2.y,c2.z,c2.w, c3.x,c3.y,c3.z,c3.w};
          #pragma unroll
          for (int jj=0;jj<16;jj++){
            const int j=jc*16+jj;
            float s0 = (j<64)? rdlane(h00,j) : rdlane(h01,j-64);
            float s1 = (j<64)? rdlane(h10,j) : rdlane(h11,j-64);
            a00 += s0*w2c[j]; a01 += s1*w2c[j];
            a10 += s0*cf[jj]; a11 += s1*cf[jj];
          }
          c0=n0; c1=n1; c2=n2; c3=n3;
        }
        // main rows' k contributions; reduce over q within each 16-group (one h)
        float pk0 = tanh_fast(a00)*s_dx[q]    + tanh_fast(a10)*s_dx[16+q];
        float pk1 = tanh_fast(a01)*s_dx[CC+q] + tanh_fast(a11)*s_dx[CC+16+q];
        #pragma unroll
        for (int o=8;o>0;o>>=1){ pk0+=__shfl_xor(pk0,o,16); pk1+=__shfl_xor(pk1,o,16); }
        if (q==0){ s_kp[h]=pk0; s_kp[32+h]=pk1; }
        // tail rows (c=32): lane-parallel partials, full-wave butterfly
        float p0=w2t[0]*h00+w2t[1]*h01;
        float p1=w2t[0]*h10+w2t[1]*h11;
        float p2=w2t[2]*h00+w2t[3]*h01;
        float p3=w2t[2]*h10+w2t[3]*h11;
        float p4=w2t[4]*h00+w2t[5]*h01;
        float p5=w2t[4]*h10+w2t[5]*h11;
        float p6=w2t[6]*h00+w2t[7]*h01;
        float p7=w2t[6]*h10+w2t[7]*h11;
        #pragma unroll
        for (int o=1;o<64;o<<=1){
          p0+=__shfl_xor(p0,o,64); p1+=__shfl_xor(p1,o,64);
          p2+=__shfl_xor(p2,o,64); p3+=__shfl_xor(p3,o,64);
          p4+=__shfl_xor(p4,o,64); p5+=__shfl_xor(p5,o,64);
          p6+=__shfl_xor(p6,o,64); p7+=__shfl_xor(p7,o,64);
        }
        if (lane==0){
          float dt0=s_dx[32], dt1=s_dx[CC+32];
          s_kt[4*wv+0]   =tanh_fast(p0+b2t[0])*dt0;
          s_kt[32+4*wv+0]=tanh_fast(p1+b2t[0])*dt1;
          s_kt[4*wv+1]   =tanh_fast(p2+b2t[1])*dt0;
          s_kt[32+4*wv+1]=tanh_fast(p3+b2t[1])*dt1;
          s_kt[4*wv+2]   =tanh_fast(p4+b2t[2])*dt0;
          s_kt[32+4*wv+2]=tanh_fast(p5+b2t[2])*dt1;
          s_kt[4*wv+3]   =tanh_fast(p6+b2t[3])*dt0;
          s_kt[32+4*wv+3]=tanh_fast(p7+b2t[3])*dt1;
        }
      }
      __syncthreads();   // sync_B: kp/kt ready
      if (t<64){         // RK4 bookkeeping: one thread per (g,h)
        float k=s_kp[t]+s_kt[t];
        float zv=s_z[t];
        if(s==0){ s_ks[t]=k;        s_zs[t]=zv+0.5f*k; }
        else if(s==1){ s_ks[t]+=2.f*k; s_zs[t]=zv+0.5f*k; }
        else if(s==2){ s_ks[t]+=2.f*k; s_zs[t]=zv+k; }
        else { float zn=zv+(s_ks[t]+k)*(1.f/6.f); s_z[t]=zn; s_zs[t]=zn; }
      }
      __syncthreads();   // sync_C: zs ready for next substage
    }
  }
  // ---- epilogue: time_embeds = zT @ rec_w.T + rec_b ----
  if (t<256){
    const int g=t>>7, d=t&127;
    float acc=rb[d];
    const float* zz=s_z+g*HH;
    const float4* rv=(const float4*)(rw + (size_t)d*HH);
    #pragma unroll
    for(int jj=0;jj<8;jj++){
      float4 vv=rv[jj];
      acc += zz[4*jj]*vv.x + zz[4*jj+1]*vv.y + zz[4*jj+2]*vv.z + zz[4*jj+3]*vv.w;
    }
    te[(size_t)(b0+g)*DD+d]=acc;
  }
}

// ================= K2: attention readout + sr (featn recomputed) ===========
__global__ __launch_bounds__(128) void k_attn(
    const float* __restrict__ emb, const int* __restrict__ iid,
    const int* __restrict__ last_nodes,
    const float* __restrict__ fcu_w, const float* __restrict__ fcv_w,
    const float* __restrict__ fcv_b, const float* __restrict__ fce_w,
    const float* __restrict__ fcsr_w,
    const float* __restrict__ te, float* __restrict__ sr){
  __shared__ float s_fn[LL*DD];      // featn tile = x/||x||
  __shared__ float s_inv[LL];
  __shared__ float s_e[LL], s_alpha[LL], s_red[2], s_sg[DD], s_fl[DD];
  const int t=threadIdx.x, b=blockIdx.x;
  for(int p=t;p<LL*DD;p+=128){
    int r=p>>7, e=p&127;
    s_fn[p]=emb[(size_t)iid[b*LL+r]*DD+e];
  }
  __syncthreads();
  { int w=t>>6, lane=t&63;
    for(int r=w;r<LL;r+=2){
      float a=s_fn[r*DD+lane], c=s_fn[r*DD+lane+64];
      float s=a*a+c*c;
      #pragma unroll
      for(int o=32;o>0;o>>=1) s+=__shfl_xor(s,o,64);
      if(lane==0) s_inv[r]=1.f/sqrtf(s);
    }
  }
  __syncthreads();
  for(int p=t;p<LL*DD;p+=128) s_fn[p]*=s_inv[p>>7];
  __syncthreads();
  int lr=last_nodes[b]-b*LL; if(lr<0||lr>=LL) lr=LL-1;   // == L-1 by construction
  s_fl[t]=s_fn[lr*DD+t];
  __syncthreads();
  float fv;
  {
    float acc=fcv_b[t];
    const float* wv=fcv_w + t*DD;
    #pragma unroll 8
    for(int j=0;j<DD;j++) acc += s_fl[j]*wv[j];
    fv=acc;
  }
  const float fce=fce_w[t];
  const float* wu=fcu_w + t*DD;
  for(int n=0;n<LL;n++){
    float fu=0.f;
    #pragma unroll 8
    for(int j=0;j<DD;j++) fu += s_fn[n*DD+j]*wu[j];
    float sv = fce/(1.f+__expf(-(fu+fv)));   // sigmoid * fce_w[d]
    #pragma unroll
    for(int o=32;o>0;o>>=1) sv += __shfl_xor(sv,o,64);
    if((t&63)==0) s_red[t>>6]=sv;
    __syncthreads();
    if(t==0) s_e[n]=s_red[0]+s_red[1];
    __syncthreads();
  }
  if(t<64){ // softmax over the 20 session nodes
    float ev=(t<LL)? s_e[t] : -1e30f;
    float m=ev;
    #pragma unroll
    for(int o=32;o>0;o>>=1) m=fmaxf(m,__shfl_xor(m,o,64));
    float ex=(t<LL)? __expf(ev-m):0.f;
    float ssum=ex;
    #pragma unroll
    for(int o=32;o>0;o>>=1) ssum+=__shfl_xor(ssum,o,64);
    if(t<LL) s_alpha[t]=ex/ssum;
  }
  __syncthreads();
  float sg=0.f;
  for(int n=0;n<LL;n++) sg += s_alpha[n]*s_fn[n*DD+t];
  s_sg[t]=sg;
  __syncthreads();
  // sr = l2n([sr_l, sr_g] @ fcsr_w.T + te)
  float pre=te[(size_t)b*DD+t];
  const float* wsr=fcsr_w + t*2*DD;
  #pragma unroll 8
  for(int j=0;j<DD;j++) pre += s_fl[j]*wsr[j];
  #pragma unroll 8
  for(int j=0;j<DD;j++) pre += s_sg[j]*wsr[DD+j];
  float ss=pre*pre;
  #pragma unroll
  for(int o=32;o>0;o>>=1) ss+=__shfl_xor(ss,o,64);
  if((t&63)==0) s_red[t>>6]=ss;
  __syncthreads();
  float tot=s_red[0]+s_red[1];
  sr[(size_t)b*DD+t]=pre/(sqrtf(tot)+1e-12f);
}

// ================= K3: logits (f32 out), inline emb-row norm ===============
// __launch_bounds__(256,2): 256-VGPR cap so er[128] stays in registers
// (bare launch_bounds risked the same silent scratch spill as round-1 k_cde).
__global__ __launch_bounds__(256, 2) void k_logits(
    const float* __restrict__ emb, const float* __restrict__ srr,
    float* __restrict__ out){
  const int v=blockIdx.x*256+threadIdx.x;
  if(v>=VN) return;
  const int bstart=blockIdx.y*256;
  float er[DD];
  {
    const float4* ev=(const float4*)emb + (size_t)v*32;
    #pragma unroll
    for(int j=0;j<32;j++){
      float4 u=ev[j];
      er[j*4+0]=u.x; er[j*4+1]=u.y; er[j*4+2]=u.z; er[j*4+3]=u.w;
    }
  }
  float nrm=0.f;
  #pragma unroll
  for(int d=0;d<DD;d++) nrm += er[d]*er[d];
  const float rn=12.f/(sqrtf(nrm)+1e-12f);
  for(int b=bstart;b<bstart+256;b++){
    const float* s=srr+(size_t)b*DD;        // wave-uniform -> scalar loads
    float acc=0.f;
    #pragma unroll
    for(int d=0;d<DD;d++) acc += er[d]*s[d];
    out[(size_t)b*VN+v]=acc*rn;
  }
}

// ================= K4: per-row logsumexp over V (online, f32) ==============
__global__ __launch_bounds__(256) void k_lse(const float* __restrict__ out,
                                             float* __restrict__ lse){
  const int b=blockIdx.x, t=threadIdx.x;
  const float4* rp=(const float4*)(out + (size_t)b*VN);
  float m=-1e30f, s=0.f;
  for(int i=t;i<VN/4;i+=256){
    float4 x=rp[i];
    float mx=fmaxf(fmaxf(x.x,x.y),fmaxf(x.z,x.w));
    if(mx>m){ s=s*__expf(m-mx); m=mx; }
    s += __expf(x.x-m)+__expf(x.y-m)+__expf(x.z-m)+__expf(x.w-m);
  }
  __shared__ float sm[256], ssb[256];
  sm[t]=m; ssb[t]=s;
  __syncthreads();
  for(int o=128;o>0;o>>=1){
    if(t<o){
      float m1=sm[t], m2=sm[t+o], s1=ssb[t], s2=ssb[t+o];
      float mm=fmaxf(m1,m2);
      sm[t]=mm; ssb[t]=s1*__expf(m1-mm)+s2*__expf(m2-mm);
    }
    __syncthreads();
  }
  if(t==0) lse[b]=sm[0]+logf(ssb[0]);
}

// ================= K5: out -= lse[b] (in place, float4) ====================
__global__ __launch_bounds__(256) void k_sub(float* __restrict__ out,
                                             const float* __restrict__ lse){
  const size_t i=(size_t)blockIdx.x*256+threadIdx.x;  // float4 index
  const int b=(int)((i*4)/VN);                         // VN%4==0: no row cross
  const float l=lse[b];
  float4* p=(float4*)out;
  float4 x=p[i];
  x.x-=l; x.y-=l; x.z-=l; x.w-=l;
  p[i]=x;
}

extern "C" void kernel_launch(void* const* d_in, const int* in_sizes, int n_in,
                              void* d_out, int out_size, void* d_ws, size_t ws_size,
                              hipStream_t stream){
  const float* emb    = (const float*)d_in[0];
  // d_in[1..6]: W1,W2,gru_* — dead code in the reference, never read
  const float* fcu_w  = (const float*)d_in[7];
  const float* fcv_w  = (const float*)d_in[8];
  const float* fcv_b  = (const float*)d_in[9];
  const float* fce_w  = (const float*)d_in[10];
  const float* fcsr_w = (const float*)d_in[11];
  const float* red_w  = (const float*)d_in[12];
  const float* red_b  = (const float*)d_in[13];
  const float* rec_w  = (const float*)d_in[14];
  const float* rec_b  = (const float*)d_in[15];
  const float* cde_w1 = (const float*)d_in[16];
  const float* cde_b1 = (const float*)d_in[17];
  const float* cde_w2 = (const float*)d_in[18];
  const float* cde_b2 = (const float*)d_in[19];
  const float* init_w = (const float*)d_in[20];
  const float* init_b = (const float*)d_in[21];
  // d_in[22]: w (edge weights) — dead code
  const float* times  = (const float*)d_in[23];
  const int* iid    = (const int*)d_in[24];
  // d_in[25..27]: src,dst,seg_ids — dead / implied by layout
  const int* last_nodes = (const int*)d_in[28];
  const int* embeds_ids = (const int*)d_in[29];
  float* out = (float*)d_out;

  float* ws  = (float*)d_ws;
  float* te  = ws;                    // B*D = 65,536 f
  float* sr  = te + (size_t)BB*DD;    // B*D = 65,536 f
  float* lse = sr + (size_t)BB*DD;    // B   =     512 f   (total 526 KB)

  k_cde   <<<BB/2, 512, 0, stream>>>(emb, embeds_ids, times, red_w, red_b,
                                     cde_w1, cde_b1, cde_w2, cde_b2,
                                     init_w, init_b, rec_w, rec_b, te);
  k_attn  <<<BB, 128, 0, stream>>>(emb, iid, last_nodes, fcu_w, fcv_w, fcv_b,
                                   fce_w, fcsr_w, te, sr);
  k_logits<<<dim3((VN+255)/256, 2), 256, 0, stream>>>(emb, sr, out);
  k_lse   <<<BB, 256, 0, stream>>>(out, lse);
  k_sub   <<<(int)(((size_t)BB*VN/4+255)/256), 256, 0, stream>>>(out, lse);
}

// Round 3
// 3264.018 us; speedup vs baseline: 1.0122x; 1.0122x over previous
//
#include <hip/hip_runtime.h>
#include <cstdint>

// Problem constants (from reference)
#define VN 100000   // vocab
#define DD 128      // D
#define BB 512      // batch
#define LL 20       // session length
#define TT 20       // time steps
#define HH 32       // H
#define CC 33       // C = H+1
#define NC (HH*CC)  // 1056

typedef unsigned int u32;

#define DEV static __device__ __forceinline__

DEV float tanh_fast(float x){ float e=__expf(2.f*x); return 1.f - 2.f/(e+1.f); }

// broadcast a lane's value wave-wide via v_readlane -> SGPR (folds into v_fma scalar src)
DEV float rdlane(float v, int l){
  return __int_as_float(__builtin_amdgcn_readlane(__float_as_int(v), l));
}

// ================= K1: fused knots + CDE RK4 scan ==========================
// Lesson from rounds 1-2: float arr[128] per-thread does NOT SROA-promote
// (VGPR stayed 84/128, FETCH 2.3-5.8 GB of scratch thrash). v4 uses NAMED
// float4 locals only (pure SSA -> mem2reg must use registers):
//   wa0..wa31 : row A   = w2[h*33+2q]       fully cached (128 f)
//   wb0..wb7  : row B   = w2[h*33+2q+1][0:32] cached (32 f)
//   rest of row B (96 f) streamed from L2 per substage (192 KB/block/substage
//   -> 6.1 MB/XCD/substage ~ 1.4us < VALU floor ~1.9us -> VALU-bound).
// 512 threads, G=2, 256 blocks (1 block/CU), __launch_bounds__(512,2) -> 256-VGPR cap.
__global__ __launch_bounds__(512, 2) void k_cde(
    const float* __restrict__ emb, const int* __restrict__ eids,
    const float* __restrict__ times,
    const float* __restrict__ red_w, const float* __restrict__ red_b,
    const float* __restrict__ w1, const float* __restrict__ b1,
    const float* __restrict__ w2, const float* __restrict__ b2,
    const float* __restrict__ iw, const float* __restrict__ ib,
    const float* __restrict__ rw, const float* __restrict__ rb,
    float* __restrict__ te){
  __shared__ float s_u[40*DD + 32*129];  // phase1: er(5120)|rw(4128); phase2: w1 (128*33)
  __shared__ float s_X[2*TT*CC];         // [g][t][c], persistent
  __shared__ float s_b1[DD];
  __shared__ float s_h1[2*DD];           // [g][j]
  __shared__ float s_z[64], s_zs[64], s_ks[64], s_kp[64], s_kt[64];
  __shared__ float s_dx[2*CC];
  const int t = threadIdx.x;
  const int b0 = blockIdx.x*2;
  const int lane = t & 63;
  const int wv = t >> 6;                 // wave 0..7
  const int h  = t >> 4;                 // 0..31
  const int q  = t & 15;                 // 0..15
  float* s_er = s_u;
  float* s_rw = s_u + 40*DD;             // phase1, rows padded to 129
  float* s_w1 = s_u;                     // phase2 alias, [j*33+h]

  // ---- phase 1: knots X[g][t][:] ----
  for (int i=t;i<HH*DD;i+=512){ int hh=i>>7, d=i&127; s_rw[hh*129+d]=red_w[i]; }
  if (t<40){ int g=t/TT, tt2=t%TT; s_X[(g*TT+tt2)*CC]=times[(b0+g)*TT+tt2]; }
  for (int pi=t;pi<40*DD;pi+=512){ int r=pi>>7, e=pi&127;
      s_er[pi]=emb[(size_t)eids[b0*TT+r]*DD+e]; }
  __syncthreads();
  for (int task=t; task<40*HH; task+=512){   // 512%32==0 -> shuffle groups aligned
    int r=task>>5, hh=task&31;
    const float* wr=s_rw+hh*129;
    const float* er=s_er+(size_t)r*DD;
    float acc=red_b[hh];
    #pragma unroll 16
    for(int e=0;e<DD;e++) acc += er[e]*wr[e];
    float ssq=acc*acc;
    #pragma unroll
    for(int o=16;o>0;o>>=1) ssq+=__shfl_xor(ssq,o,32);
    s_X[r*CC+1+hh]=acc/(sqrtf(ssq)+1e-12f);   // fode = l2n(...) into X[...,1+h]
  }
  __syncthreads();                            // fode readers done; union free

  // ---- w2 -> named registers (loaded once, after phase 1 to shorten liveness) ----
  const float4* ra4 = (const float4*)(w2 + (size_t)(h*CC + 2*q)*DD);  // row A
  const float4* rb4 = ra4 + 32;                                        // row B
  float4 wa0 =ra4[0],  wa1 =ra4[1],  wa2 =ra4[2],  wa3 =ra4[3],
         wa4 =ra4[4],  wa5 =ra4[5],  wa6 =ra4[6],  wa7 =ra4[7],
         wa8 =ra4[8],  wa9 =ra4[9],  wa10=ra4[10], wa11=ra4[11],
         wa12=ra4[12], wa13=ra4[13], wa14=ra4[14], wa15=ra4[15],
         wa16=ra4[16], wa17=ra4[17], wa18=ra4[18], wa19=ra4[19],
         wa20=ra4[20], wa21=ra4[21], wa22=ra4[22], wa23=ra4[23],
         wa24=ra4[24], wa25=ra4[25], wa26=ra4[26], wa27=ra4[27],
         wa28=ra4[28], wa29=ra4[29], wa30=ra4[30], wa31=ra4[31];
  float4 wb0=rb4[0], wb1=rb4[1], wb2=rb4[2], wb3=rb4[3],
         wb4v=rb4[4], wb5=rb4[5], wb6=rb4[6], wb7=rb4[7];
  const float b2A = b2[h*CC+2*q];
  const float b2B = b2[h*CC+2*q+1];
  // tail rows n=(4wv+r)*33+32: lane holds elems [lane], [64+lane] (named scalars)
  float wt0,wt1,wt2,wt3,wt4,wt5,wt6,wt7, bt0,bt1,bt2,bt3;
  { const float* tr=w2+(size_t)((4*wv+0)*CC+32)*DD; wt0=tr[lane]; wt1=tr[64+lane]; bt0=b2[(4*wv+0)*CC+32]; }
  { const float* tr=w2+(size_t)((4*wv+1)*CC+32)*DD; wt2=tr[lane]; wt3=tr[64+lane]; bt1=b2[(4*wv+1)*CC+32]; }
  { const float* tr=w2+(size_t)((4*wv+2)*CC+32)*DD; wt4=tr[lane]; wt5=tr[64+lane]; bt2=b2[(4*wv+2)*CC+32]; }
  { const float* tr=w2+(size_t)((4*wv+3)*CC+32)*DD; wt6=tr[lane]; wt7=tr[64+lane]; bt3=b2[(4*wv+3)*CC+32]; }

  // ---- phase 2 weights: w1 (stride 33, conflict-free b32 reads), b1 ----
  for (int i=t;i<DD*HH;i+=512){ int j=i>>5, hh=i&31; s_w1[j*33+hh]=w1[i]; }
  if (t<DD) s_b1[t]=b1[t];
  // ---- z0 = X[:,0] @ init_w.T + init_b ----
  if (t<64){
    int g=t>>5, hh=t&31;
    float acc=ib[hh];
    const float* x0=s_X+(size_t)(g*TT)*CC;
    #pragma unroll
    for(int c=0;c<CC;c++) acc += x0[c]*iw[hh*CC+c];
    s_z[t]=acc; s_zs[t]=acc;
  }
  __syncthreads();   // w1/b1/z0 ready

// per-element MAC: broadcast h1[g][E] via readlane (constant lane after expansion)
#define EL(E, WAe, WBe) { \
  const float s0_ = ((E)<64)? rdlane(h00,(E)&63) : rdlane(h01,(E)&63); \
  const float s1_ = ((E)<64)? rdlane(h10,(E)&63) : rdlane(h11,(E)&63); \
  aA0 += s0_*(WAe); aA1 += s1_*(WAe); \
  aB0 += s0_*(WBe); aB1 += s1_*(WBe); }
#define QC(J, WAV, WBV) \
  EL(4*(J)+0, (WAV).x, (WBV).x) \
  EL(4*(J)+1, (WAV).y, (WBV).y) \
  EL(4*(J)+2, (WAV).z, (WBV).z) \
  EL(4*(J)+3, (WAV).w, (WBV).w)
#define QS(J, WAV) { const float4 bv_ = rb4[J]; \
  EL(4*(J)+0, (WAV).x, bv_.x) \
  EL(4*(J)+1, (WAV).y, bv_.y) \
  EL(4*(J)+2, (WAV).z, bv_.z) \
  EL(4*(J)+3, (WAV).w, bv_.w) }

  for (int step=0; step<TT-1; step++){
    if (t<2*CC){ int g=t/CC, c=t-g*CC;
      s_dx[t]=s_X[(g*TT+step+1)*CC+c]-s_X[(g*TT+step)*CC+c]; }
    for (int s=0;s<4;s++){
      // ---- stage A: h1 = relu(zs @ w1.T + b1) ----
      if (t<256){
        const int g=t>>7, j=t&127, gb=(t>>7)*32;
        float zsv=s_zs[lane];
        float acc=s_b1[j];
        const float* wj=s_w1+j*33;
        #pragma unroll
        for(int hh=0;hh<HH;hh++) acc += rdlane(zsv, gb+hh)*wj[hh];
        s_h1[g*DD+j]=fmaxf(acc,0.f);
      }
      __syncthreads();   // sync_A: h1 (and s_dx) ready
      {
        const float h00=s_h1[lane],    h01=s_h1[64+lane];     // g=0
        const float h10=s_h1[DD+lane], h11=s_h1[DD+64+lane];  // g=1
        float aA0=b2A, aA1=b2A, aB0=b2B, aB1=b2B;
        QC(0,wa0,wb0)   QC(1,wa1,wb1)   QC(2,wa2,wb2)   QC(3,wa3,wb3)
        QC(4,wa4,wb4v)  QC(5,wa5,wb5)   QC(6,wa6,wb6)   QC(7,wa7,wb7)
        QS(8,wa8)   QS(9,wa9)   QS(10,wa10) QS(11,wa11)
        QS(12,wa12) QS(13,wa13) QS(14,wa14) QS(15,wa15)
        QS(16,wa16) QS(17,wa17) QS(18,wa18) QS(19,wa19)
        QS(20,wa20) QS(21,wa21) QS(22,wa22) QS(23,wa23)
        QS(24,wa24) QS(25,wa25) QS(26,wa26) QS(27,wa27)
        QS(28,wa28) QS(29,wa29) QS(30,wa30) QS(31,wa31)
        // main-row k contributions; reduce over q within each 16-group (one h)
        float pk0 = tanh_fast(aA0)*s_dx[2*q]    + tanh_fast(aB0)*s_dx[2*q+1];
        float pk1 = tanh_fast(aA1)*s_dx[CC+2*q] + tanh_fast(aB1)*s_dx[CC+2*q+1];
        #pragma unroll
        for (int o=8;o>0;o>>=1){ pk0+=__shfl_xor(pk0,o,16); pk1+=__shfl_xor(pk1,o,16); }
        if (q==0){ s_kp[h]=pk0; s_kp[32+h]=pk1; }
        // tail rows (c=32): lane-parallel partials, full-wave butterfly
        float p0=wt0*h00+wt1*h01;
        float p1=wt0*h10+wt1*h11;
        float p2=wt2*h00+wt3*h01;
        float p3=wt2*h10+wt3*h11;
        float p4=wt4*h00+wt5*h01;
        float p5=wt4*h10+wt5*h11;
        float p6=wt6*h00+wt7*h01;
        float p7=wt6*h10+wt7*h11;
        #pragma unroll
        for (int o=1;o<64;o<<=1){
          p0+=__shfl_xor(p0,o,64); p1+=__shfl_xor(p1,o,64);
          p2+=__shfl_xor(p2,o,64); p3+=__shfl_xor(p3,o,64);
          p4+=__shfl_xor(p4,o,64); p5+=__shfl_xor(p5,o,64);
          p6+=__shfl_xor(p6,o,64); p7+=__shfl_xor(p7,o,64);
        }
        if (lane==0){
          float dt0=s_dx[32], dt1=s_dx[CC+32];
          s_kt[4*wv+0]   =tanh_fast(p0+bt0)*dt0;
          s_kt[32+4*wv+0]=tanh_fast(p1+bt0)*dt1;
          s_kt[4*wv+1]   =tanh_fast(p2+bt1)*dt0;
          s_kt[32+4*wv+1]=tanh_fast(p3+bt1)*dt1;
          s_kt[4*wv+2]   =tanh_fast(p4+bt2)*dt0;
          s_kt[32+4*wv+2]=tanh_fast(p5+bt2)*dt1;
          s_kt[4*wv+3]   =tanh_fast(p6+bt3)*dt0;
          s_kt[32+4*wv+3]=tanh_fast(p7+bt3)*dt1;
        }
      }
      __syncthreads();   // sync_B: kp/kt ready
      if (t<64){         // RK4 bookkeeping: one thread per (g,h)
        float k=s_kp[t]+s_kt[t];
        float zv=s_z[t];
        if(s==0){ s_ks[t]=k;        s_zs[t]=zv+0.5f*k; }
        else if(s==1){ s_ks[t]+=2.f*k; s_zs[t]=zv+0.5f*k; }
        else if(s==2){ s_ks[t]+=2.f*k; s_zs[t]=zv+k; }
        else { float zn=zv+(s_ks[t]+k)*(1.f/6.f); s_z[t]=zn; s_zs[t]=zn; }
      }
      __syncthreads();   // sync_C: zs ready for next substage
    }
  }
#undef EL
#undef QC
#undef QS
  // ---- epilogue: time_embeds = zT @ rec_w.T + rec_b ----
  if (t<256){
    const int g=t>>7, d=t&127;
    float acc=rb[d];
    const float* zz=s_z+g*HH;
    const float4* rv=(const float4*)(rw + (size_t)d*HH);
    #pragma unroll
    for(int jj=0;jj<8;jj++){
      float4 vv=rv[jj];
      acc += zz[4*jj]*vv.x + zz[4*jj+1]*vv.y + zz[4*jj+2]*vv.z + zz[4*jj+3]*vv.w;
    }
    te[(size_t)(b0+g)*DD+d]=acc;
  }
}

// ================= K2: attention readout + sr (featn recomputed) ===========
__global__ __launch_bounds__(128) void k_attn(
    const float* __restrict__ emb, const int* __restrict__ iid,
    const int* __restrict__ last_nodes,
    const float* __restrict__ fcu_w, const float* __restrict__ fcv_w,
    const float* __restrict__ fcv_b, const float* __restrict__ fce_w,
    const float* __restrict__ fcsr_w,
    const float* __restrict__ te, float* __restrict__ sr){
  __shared__ float s_fn[LL*DD];      // featn tile = x/||x||
  __shared__ float s_inv[LL];
  __shared__ float s_e[LL], s_alpha[LL], s_red[2], s_sg[DD], s_fl[DD];
  const int t=threadIdx.x, b=blockIdx.x;
  for(int p=t;p<LL*DD;p+=128){
    int r=p>>7, e=p&127;
    s_fn[p]=emb[(size_t)iid[b*LL+r]*DD+e];
  }
  __syncthreads();
  { int w=t>>6, lane=t&63;
    for(int r=w;r<LL;r+=2){
      float a=s_fn[r*DD+lane], c=s_fn[r*DD+lane+64];
      float s=a*a+c*c;
      #pragma unroll
      for(int o=32;o>0;o>>=1) s+=__shfl_xor(s,o,64);
      if(lane==0) s_inv[r]=1.f/sqrtf(s);
    }
  }
  __syncthreads();
  for(int p=t;p<LL*DD;p+=128) s_fn[p]*=s_inv[p>>7];
  __syncthreads();
  int lr=last_nodes[b]-b*LL; if(lr<0||lr>=LL) lr=LL-1;   // == L-1 by construction
  s_fl[t]=s_fn[lr*DD+t];
  __syncthreads();
  float fv;
  {
    float acc=fcv_b[t];
    const float* wv=fcv_w + t*DD;
    #pragma unroll 8
    for(int j=0;j<DD;j++) acc += s_fl[j]*wv[j];
    fv=acc;
  }
  const float fce=fce_w[t];
  const float* wu=fcu_w + t*DD;
  for(int n=0;n<LL;n++){
    float fu=0.f;
    #pragma unroll 8
    for(int j=0;j<DD;j++) fu += s_fn[n*DD+j]*wu[j];
    float sv = fce/(1.f+__expf(-(fu+fv)));   // sigmoid * fce_w[d]
    #pragma unroll
    for(int o=32;o>0;o>>=1) sv += __shfl_xor(sv,o,64);
    if((t&63)==0) s_red[t>>6]=sv;
    __syncthreads();
    if(t==0) s_e[n]=s_red[0]+s_red[1];
    __syncthreads();
  }
  if(t<64){ // softmax over the 20 session nodes
    float ev=(t<LL)? s_e[t] : -1e30f;
    float m=ev;
    #pragma unroll
    for(int o=32;o>0;o>>=1) m=fmaxf(m,__shfl_xor(m,o,64));
    float ex=(t<LL)? __expf(ev-m):0.f;
    float ssum=ex;
    #pragma unroll
    for(int o=32;o>0;o>>=1) ssum+=__shfl_xor(ssum,o,64);
    if(t<LL) s_alpha[t]=ex/ssum;
  }
  __syncthreads();
  float sg=0.f;
  for(int n=0;n<LL;n++) sg += s_alpha[n]*s_fn[n*DD+t];
  s_sg[t]=sg;
  __syncthreads();
  // sr = l2n([sr_l, sr_g] @ fcsr_w.T + te)
  float pre=te[(size_t)b*DD+t];
  const float* wsr=fcsr_w + t*2*DD;
  #pragma unroll 8
  for(int j=0;j<DD;j++) pre += s_fl[j]*wsr[j];
  #pragma unroll 8
  for(int j=0;j<DD;j++) pre += s_sg[j]*wsr[DD+j];
  float ss=pre*pre;
  #pragma unroll
  for(int o=32;o>0;o>>=1) ss+=__shfl_xor(ss,o,64);
  if((t&63)==0) s_red[t>>6]=ss;
  __syncthreads();
  float tot=s_red[0]+s_red[1];
  sr[(size_t)b*DD+t]=pre/(sqrtf(tot)+1e-12f);
}

// ================= K3: logits (f32 out), inline emb-row norm ===============
// __launch_bounds__(256,2): 256-VGPR cap so er[128] stays in registers
__global__ __launch_bounds__(256, 2) void k_logits(
    const float* __restrict__ emb, const float* __restrict__ srr,
    float* __restrict__ out){
  const int v=blockIdx.x*256+threadIdx.x;
  if(v>=VN) return;
  const int bstart=blockIdx.y*256;
  float er[DD];
  {
    const float4* ev=(const float4*)emb + (size_t)v*32;
    #pragma unroll
    for(int j=0;j<32;j++){
      float4 u=ev[j];
      er[j*4+0]=u.x; er[j*4+1]=u.y; er[j*4+2]=u.z; er[j*4+3]=u.w;
    }
  }
  float nrm=0.f;
  #pragma unroll
  for(int d=0;d<DD;d++) nrm += er[d]*er[d];
  const float rn=12.f/(sqrtf(nrm)+1e-12f);
  for(int b=bstart;b<bstart+256;b++){
    const float* s=srr+(size_t)b*DD;        // wave-uniform -> scalar loads
    float acc=0.f;
    #pragma unroll
    for(int d=0;d<DD;d++) acc += er[d]*s[d];
    out[(size_t)b*VN+v]=acc*rn;
  }
}

// ================= K4: per-row logsumexp over V (online, f32) ==============
__global__ __launch_bounds__(256) void k_lse(const float* __restrict__ out,
                                             float* __restrict__ lse){
  const int b=blockIdx.x, t=threadIdx.x;
  const float4* rp=(const float4*)(out + (size_t)b*VN);
  float m=-1e30f, s=0.f;
  for(int i=t;i<VN/4;i+=256){
    float4 x=rp[i];
    float mx=fmaxf(fmaxf(x.x,x.y),fmaxf(x.z,x.w));
    if(mx>m){ s=s*__expf(m-mx); m=mx; }
    s += __expf(x.x-m)+__expf(x.y-m)+__expf(x.z-m)+__expf(x.w-m);
  }
  __shared__ float sm[256], ssb[256];
  sm[t]=m; ssb[t]=s;
  __syncthreads();
  for(int o=128;o>0;o>>=1){
    if(t<o){
      float m1=sm[t], m2=sm[t+o], s1=ssb[t], s2=ssb[t+o];
      float mm=fmaxf(m1,m2);
      sm[t]=mm; ssb[t]=s1*__expf(m1-mm)+s2*__expf(m2-mm);
    }
    __syncthreads();
  }
  if(t==0) lse[b]=sm[0]+logf(ssb[0]);
}

// ================= K5: out -= lse[b] (in place, float4) ====================
__global__ __launch_bounds__(256) void k_sub(float* __restrict__ out,
                                             const float* __restrict__ lse){
  const size_t i=(size_t)blockIdx.x*256+threadIdx.x;  // float4 index
  const int b=(int)((i*4)/VN);                         // VN%4==0: no row cross
  const float l=lse[b];
  float4* p=(float4*)out;
  float4 x=p[i];
  x.x-=l; x.y-=l; x.z-=l; x.w-=l;
  p[i]=x;
}

extern "C" void kernel_launch(void* const* d_in, const int* in_sizes, int n_in,
                              void* d_out, int out_size, void* d_ws, size_t ws_size,
                              hipStream_t stream){
  const float* emb    = (const float*)d_in[0];
  // d_in[1..6]: W1,W2,gru_* — dead code in the reference, never read
  const float* fcu_w  = (const float*)d_in[7];
  const float* fcv_w  = (const float*)d_in[8];
  const float* fcv_b  = (const float*)d_in[9];
  const float* fce_w  = (const float*)d_in[10];
  const float* fcsr_w = (const float*)d_in[11];
  const float* red_w  = (const float*)d_in[12];
  const float* red_b  = (const float*)d_in[13];
  const float* rec_w  = (const float*)d_in[14];
  const float* rec_b  = (const float*)d_in[15];
  const float* cde_w1 = (const float*)d_in[16];
  const float* cde_b1 = (const float*)d_in[17];
  const float* cde_w2 = (const float*)d_in[18];
  const float* cde_b2 = (const float*)d_in[19];
  const float* init_w = (const float*)d_in[20];
  const float* init_b = (const float*)d_in[21];
  // d_in[22]: w (edge weights) — dead code
  const float* times  = (const float*)d_in[23];
  const int* iid    = (const int*)d_in[24];
  // d_in[25..27]: src,dst,seg_ids — dead / implied by layout
  const int* last_nodes = (const int*)d_in[28];
  const int* embeds_ids = (const int*)d_in[29];
  float* out = (float*)d_out;

  float* ws  = (float*)d_ws;
  float* te  = ws;                    // B*D = 65,536 f
  float* sr  = te + (size_t)BB*DD;    // B*D = 65,536 f
  float* lse = sr + (size_t)BB*DD;    // B   =     512 f   (total 526 KB)

  k_cde   <<<BB/2, 512, 0, stream>>>(emb, embeds_ids, times, red_w, red_b,
                                     cde_w1, cde_b1, cde_w2, cde_b2,
                                     init_w, init_b, rec_w, rec_b, te);
  k_attn  <<<BB, 128, 0, stream>>>(emb, iid, last_nodes, fcu_w, fcv_w, fcv_b,
                                   fce_w, fcsr_w, te, sr);
  k_logits<<<dim3((VN+255)/256, 2), 256, 0, stream>>>(emb, sr, out);
  k_lse   <<<BB, 256, 0, stream>>>(out, lse);
  k_sub   <<<(int)(((size_t)BB*VN/4+255)/256), 256, 0, stream>>>(out, lse);
}